// Round 7
// baseline (335.789 us; speedup 1.0000x reference)
//
#include <hip/hip_runtime.h>
#include <math.h>

#define BZ   8
#define DDIM 128
#define NN   2048
#define KSEL 30
#define KEEP 1024
#define ROWS 8

// ---------- block reductions (blockDim == 256) ----------
__device__ __forceinline__ double blockReduceD(double x, double* lds) {
  #pragma unroll
  for (int off = 32; off; off >>= 1) x += __shfl_down(x, off, 64);
  int wv = threadIdx.x >> 6;
  __syncthreads();
  if ((threadIdx.x & 63) == 0) lds[wv] = x;
  __syncthreads();
  return lds[0] + lds[1] + lds[2] + lds[3];
}

__device__ __forceinline__ long long blockReduceLL(long long x, long long* lds) {
  #pragma unroll
  for (int off = 32; off; off >>= 1) x += __shfl_down(x, off, 64);
  int wv = threadIdx.x >> 6;
  __syncthreads();
  if ((threadIdx.x & 63) == 0) lds[wv] = x;
  __syncthreads();
  return lds[0] + lds[1] + lds[2] + lds[3];
}

// ---------- K1: per-(b,feature) mean/std(ddof=1) + normalize (fp32 out) ----
__global__ __launch_bounds__(256) void k_norm(const float* __restrict__ data,
                                              float* __restrict__ xnT) {
  __shared__ double lds[4];
  __shared__ float msd[2];
  const int blk = blockIdx.x;
  const int t = threadIdx.x;
  const float* src = data + (size_t)blk * NN;
  float* dst = xnT + (size_t)blk * NN;
  float v[8];
  double s = 0.0, s2 = 0.0;
  #pragma unroll
  for (int q = 0; q < 8; ++q) {
    v[q] = src[t + q * 256];
    double d = (double)v[q];
    s += d;
    s2 = fma(d, d, s2);
  }
  s  = blockReduceD(s, lds);
  s2 = blockReduceD(s2, lds);
  if (t == 0) {
    double mean = s * (1.0 / 2048.0);
    double var = (s2 - s * mean) / 2047.0;
    if (var < 0.0) var = 0.0;
    msd[0] = (float)mean;
    msd[1] = (float)sqrt(var);
  }
  __syncthreads();
  const float mean = msd[0];
  const float den = msd[1] + 1e-6f;
  #pragma unroll
  for (int q = 0; q < 8; ++q)
    dst[t + q * 256] = (v[q] - mean) / den;
}

// ---------- K2: sq[b][n] = sum_d Xn^2 (fp64 chain, fp32 input) ----------
__global__ __launch_bounds__(256) void k_sq(const float* __restrict__ xnT,
                                            double* __restrict__ sq) {
  const int g = blockIdx.x * 256 + threadIdx.x;
  const int b = g >> 11, n = g & 2047;
  const float* X = xnT + (size_t)b * DDIM * NN + n;
  double s = 0.0;
  for (int d = 0; d < DDIM; ++d) {
    double x = (double)X[(size_t)d * NN];
    s = fma(x, x, s);
  }
  sq[g] = s;
}

// ---------- K3: cyclic-halved symmetric fp64 distance GEMM, TILE=16 -------
// grid 1024: blk = g*8 + b (b = blk&7 -> XCD pin), g in [0,128).
// Rows [16g,16g+16); cols = 1024-wide cyclic window [16g, 16g+1024).
// Covers tile separations 0..63; separation 64 handled by k_gemm_anti16.
// fp32 loads widened in-register ((double)f is exact) -> fma chain bitwise
// identical to rounds 4-6. Stores [i][j] and bitwise-identical mirror [j][i].
__global__ __launch_bounds__(1024, 4) void k_gemm_cyc16(
    const float* __restrict__ xnT, const double* __restrict__ sq,
    float* __restrict__ distM) {
  __shared__ double rowd[DDIM][16];   // 16 KB
  const int b = blockIdx.x & 7;
  const int g = blockIdx.x >> 3;      // 0..127
  const int i0 = g << 4;
  const int t = threadIdx.x;          // 0..1023
  const float* Xb = xnT + (size_t)b * DDIM * NN;

  #pragma unroll
  for (int q = 0; q < 2; ++q) {
    const int idx = (t << 1) + q;     // 0..2047
    const int d = idx >> 4, r = idx & 15;
    rowd[d][r] = (double)Xb[((size_t)d << 11) + i0 + r];
  }
  __syncthreads();

  const int c = (i0 + t) & (NN - 1);  // this thread's column
  const float* colp = Xb + c;

  double acc[16];
  #pragma unroll
  for (int r = 0; r < 16; ++r) acc[r] = 0.0;

  float pf = colp[0];
  for (int d = 0; d < DDIM; ++d) {
    const float pn = (d < DDIM - 1) ? colp[(size_t)(d + 1) << 11] : 0.0f;
    const double cv = (double)pf;
    const double2* rp = (const double2*)&rowd[d][0];
    #pragma unroll
    for (int h = 0; h < 8; ++h) {
      const double2 rv = rp[h];
      acc[2 * h]     = fma(rv.x, cv, acc[2 * h]);
      acc[2 * h + 1] = fma(rv.y, cv, acc[2 * h + 1]);
    }
    pf = pn;
  }

  const double* sqb = sq + (b << 11);
  const double sqc = sqb[c];
  float f[16];
  #pragma unroll
  for (int r = 0; r < 16; ++r) {
    double d2 = (sqb[i0 + r] + sqc) - 2.0 * acc[r];
    if (d2 < 0.0) d2 = 0.0;
    f[r] = (float)sqrt(d2);           // identical rounding point as before
    distM[(((size_t)((b << 11) + i0 + r)) << 11) + c] = f[r];
  }
  // mirror: row c, cols i0..i0+15 (bitwise-identical by commutativity)
  float* mrow = distM + (((size_t)((b << 11) + c)) << 11) + i0;
  *(float4*)(mrow)      = make_float4(f[0],  f[1],  f[2],  f[3]);
  *(float4*)(mrow + 4)  = make_float4(f[4],  f[5],  f[6],  f[7]);
  *(float4*)(mrow + 8)  = make_float4(f[8],  f[9],  f[10], f[11]);
  *(float4*)(mrow + 12) = make_float4(f[12], f[13], f[14], f[15]);
}

// ---------- K3a: antipodal 16x16 tiles (separation 64) ----------
// grid 512: blk = g*8 + b, g in [0,64). Rows [16g,16g+16) x cols [16g+1024,+16).
__global__ __launch_bounds__(256) void k_gemm_anti16(
    const float* __restrict__ xnT, const double* __restrict__ sq,
    float* __restrict__ distM) {
  __shared__ double rowd[DDIM][16];   // 16 KB
  __shared__ double cold[DDIM][16];   // 16 KB
  const int b = blockIdx.x & 7;
  const int g = blockIdx.x >> 3;      // 0..63
  const int i0 = g << 4;
  const int j0 = i0 + 1024;
  const int t = threadIdx.x;          // 0..255
  const float* Xb = xnT + (size_t)b * DDIM * NN;
  #pragma unroll
  for (int q = 0; q < 8; ++q) {
    const int idx = (t << 3) + q;     // 0..2047
    const int d = idx >> 4, r = idx & 15;
    rowd[d][r] = (double)Xb[((size_t)d << 11) + i0 + r];
    cold[d][r] = (double)Xb[((size_t)d << 11) + j0 + r];
  }
  __syncthreads();
  const int r = t >> 4, q = t & 15;
  double acc = 0.0;
  for (int d = 0; d < DDIM; ++d)
    acc = fma(rowd[d][r], cold[d][q], acc);
  const double* sqb = sq + (b << 11);
  double d2 = (sqb[i0 + r] + sqb[j0 + q]) - 2.0 * acc;
  if (d2 < 0.0) d2 = 0.0;
  const float f = (float)sqrt(d2);
  distM[(((size_t)((b << 11) + i0 + r)) << 11) + j0 + q] = f;
  distM[(((size_t)((b << 11) + j0 + q)) << 11) + i0 + r] = f;
}

// ---------- K3b: wave-per-row radix select (count(u<mid) form) ----------
__global__ __launch_bounds__(256) void k_sel(const float* __restrict__ dist,
                                             float* __restrict__ kth) {
  const int row = (blockIdx.x << 2) + (threadIdx.x >> 6);
  const int l = threadIdx.x & 63;
  const float4* r4 = (const float4*)(dist + ((size_t)row << 11));
  unsigned u[32];
  #pragma unroll
  for (int jj = 0; jj < 8; ++jj) {
    const float4 fv = r4[(jj << 6) + l];
    u[jj * 4 + 0] = __float_as_uint(fv.x);
    u[jj * 4 + 1] = __float_as_uint(fv.y);
    u[jj * 4 + 2] = __float_as_uint(fv.z);
    u[jj * 4 + 3] = __float_as_uint(fv.w);
  }
  unsigned pref = 0;
  for (int bit = 30; bit >= 0; --bit) {
    const unsigned mid = pref | (1u << bit);
    int c = 0;
    #pragma unroll
    for (int k = 0; k < 32; ++k)
      c += (int)__popcll(__ballot(u[k] < mid));
    if (c <= KSEL) pref = mid;
  }
  if (l == 0) kth[row] = __uint_as_float(pref);
}

// ---------- K4: mean of 2048 floats -> float ----------
__global__ __launch_bounds__(256) void k_mean2048(const float* __restrict__ in,
                                                  float* __restrict__ out) {
  __shared__ double lds[4];
  const int b = blockIdx.x, t = threadIdx.x;
  const float* p = in + (b << 11);
  double s = 0.0;
  #pragma unroll
  for (int q = 0; q < 8; ++q) s += (double)p[t + q * 256];
  s = blockReduceD(s, lds);
  if (t == 0) out[b] = (float)(s * (1.0 / 2048.0));
}

// ---------- K5: counts, one block per row i, all 8 batches ----------
__global__ __launch_bounds__(256) void k_count_all(
    const float* __restrict__ dist, const float* __restrict__ adj,
    const float* __restrict__ Rf,
    float* __restrict__ samples, float* __restrict__ neigh,
    float* __restrict__ degree) {
  __shared__ int pS[4], pN[4];
  const int i = blockIdx.x;
  const int t = threadIdx.x, w = t >> 6, l = t & 63;
  const float4* arow = (const float4*)(adj + ((size_t)i << 11)) + (t << 1);
  const float4 a0 = arow[0], a1 = arow[1];
  const float a[8] = {a0.x, a0.y, a0.z, a0.w, a1.x, a1.y, a1.z, a1.w};
  int dc = 0;
  #pragma unroll
  for (int q = 0; q < 8; ++q)
    dc += (int)__popcll(__ballot(a[q] != 0.0f));
  if (l == 0) pS[w] = dc;
  __syncthreads();
  if (t == 0) degree[i] = (float)(pS[0] + pS[1] + pS[2] + pS[3]);

  for (int b = 0; b < BZ; ++b) {
    const float R = Rf[b];
    const float4* drow =
        (const float4*)(dist + (((size_t)((b << 11) + i)) << 11)) + (t << 1);
    const float4 d0 = drow[0], d1 = drow[1];
    const float f[8] = {d0.x, d0.y, d0.z, d0.w, d1.x, d1.y, d1.z, d1.w};
    int sN = 0, nN = 0;
    #pragma unroll
    for (int q = 0; q < 8; ++q) {
      sN += (int)__popcll(__ballot(f[q] < R));
      nN += (int)__popcll(__ballot((a[q] != 0.0f) && (f[q] != 0.0f) && (f[q] < R)));
    }
    __syncthreads();
    if (l == 0) { pS[w] = sN; pN[w] = nN; }
    __syncthreads();
    if (t == 0) {
      samples[(b << 11) + i] = (float)(pS[0] + pS[1] + pS[2] + pS[3]);
      neigh[(b << 11) + i]   = (float)(pN[0] + pN[1] + pN[2] + pN[3]);
    }
  }
}

// ---------- tier-3 fallback (tiny ws): round-2 fused kernel ----------
template<int MODE>
__global__ __launch_bounds__(256, 2) void k_dist(
    const float* __restrict__ xnT, const double* __restrict__ sq,
    float* __restrict__ kth, float* __restrict__ distOut,
    const float* __restrict__ adj, const float* __restrict__ Rf,
    float* __restrict__ samples, float* __restrict__ neigh,
    float* __restrict__ degree) {
  __shared__ double rowd[DDIM][ROWS];
  __shared__ float dtile[ROWS][NN];
  __shared__ long long ldsLL[4];
  const int b = blockIdx.x >> 8;
  const int i0 = (blockIdx.x & 255) * ROWS;
  const int t = threadIdx.x;
  const float* Xb = xnT + (size_t)b * DDIM * NN;
  #pragma unroll
  for (int q = 0; q < 4; ++q) {
    const int idx = t + q * 256;
    const int d = idx >> 3, r = idx & 7;
    rowd[d][r] = (double)Xb[(size_t)d * NN + i0 + r];
  }
  __syncthreads();
  double acc[ROWS][8];
  #pragma unroll
  for (int r = 0; r < ROWS; ++r)
    #pragma unroll
    for (int q = 0; q < 8; ++q) acc[r][q] = 0.0;
  for (int d = 0; d < DDIM; ++d) {
    const float4* c4 = (const float4*)(Xb + ((size_t)d << 11)) + (t << 1);
    const float4 c0 = c4[0], c1 = c4[1];
    double cd[8];
    cd[0] = (double)c0.x; cd[1] = (double)c0.y;
    cd[2] = (double)c0.z; cd[3] = (double)c0.w;
    cd[4] = (double)c1.x; cd[5] = (double)c1.y;
    cd[6] = (double)c1.z; cd[7] = (double)c1.w;
    #pragma unroll
    for (int r = 0; r < ROWS; ++r) {
      const double rv = rowd[d][r];
      #pragma unroll
      for (int q = 0; q < 8; ++q) acc[r][q] = fma(rv, cd[q], acc[r][q]);
    }
  }
  const double* sqb = sq + (b << 11);
  const float R = (MODE == 2) ? Rf[b] : 0.0f;
  long long pk[ROWS];
  #pragma unroll
  for (int r = 0; r < ROWS; ++r) {
    const double sqi = sqb[i0 + r];
    float f8[8];
    #pragma unroll
    for (int q = 0; q < 8; ++q) {
      double d2 = (sqi + sqb[(t << 3) + q]) - 2.0 * acc[r][q];
      if (d2 < 0.0) d2 = 0.0;
      f8[q] = (float)sqrt(d2);
    }
    if (MODE < 2) {
      #pragma unroll
      for (int q = 0; q < 8; ++q) dtile[r][(t << 3) + q] = f8[q];
    } else {
      const float* arow = adj + (size_t)(i0 + r) * NN + (t << 3);
      int sN = 0, nN = 0, dc = 0;
      #pragma unroll
      for (int q = 0; q < 8; ++q) {
        const float a = arow[q];
        sN += (f8[q] < R) ? 1 : 0;
        nN += ((a != 0.0f) && (f8[q] != 0.0f) && (f8[q] < R)) ? 1 : 0;
        dc += (a != 0.0f) ? 1 : 0;
      }
      pk[r] = (long long)sN | ((long long)nN << 12) | ((long long)dc << 24);
    }
  }
  if (MODE < 2) {
    __syncthreads();
    const int w = t >> 6, l = t & 63;
    #pragma unroll
    for (int rr = 0; rr < 2; ++rr) {
      const int r = w * 2 + rr;
      unsigned u[32];
      #pragma unroll
      for (int k = 0; k < 32; ++k) u[k] = __float_as_uint(dtile[r][k * 64 + l]);
      unsigned pref = 0;
      int want = KSEL;
      for (int bit = 30; bit >= 0; --bit) {
        const unsigned ps = pref >> bit;
        int c = 0;
        #pragma unroll
        for (int k = 0; k < 32; ++k) c += ((u[k] >> bit) == ps) ? 1 : 0;
        #pragma unroll
        for (int off = 1; off < 64; off <<= 1) c += __shfl_xor(c, off, 64);
        if (want >= c) { want -= c; pref |= (1u << bit); }
      }
      if (l == 0) kth[(b << 11) + i0 + r] = __uint_as_float(pref);
    }
  } else {
    #pragma unroll
    for (int r = 0; r < ROWS; ++r) {
      const long long s = blockReduceLL(pk[r], ldsLL);
      if (t == 0) {
        const int g = (b << 11) + i0 + r;
        samples[g] = (float)(s & 0xFFF);
        neigh[g]   = (float)((s >> 12) & 0xFFF);
        if (b == 0) degree[i0 + r] = (float)((s >> 24) & 0xFFF);
      }
    }
  }
}

// ---------- K6+K7a fused: mf = mean(samples) then total_score ----------
__global__ __launch_bounds__(256) void k_scoremean(const float* __restrict__ samples,
                                                   const float* __restrict__ neigh,
                                                   const float* __restrict__ degree,
                                                   float* __restrict__ score) {
  __shared__ double lds[4];
  __shared__ float mfs;
  const int b = blockIdx.x, t = threadIdx.x;
  const float* p = samples + (b << 11);
  double s = 0.0;
  #pragma unroll
  for (int q = 0; q < 8; ++q) s += (double)p[t + q * 256];
  s = blockReduceD(s, lds);
  if (t == 0) mfs = (float)(s * (1.0 / 2048.0));
  __syncthreads();
  const float mf = mfs;
  #pragma unroll
  for (int q = 0; q < 8; ++q) {
    const int i = t + q * 256;
    const int g = (b << 11) + i;
    const float sp = neigh[g] / degree[i];
    const float sv = samples[g];
    const float tp = sv / (sv + mf);
    score[g] = (2.0f - sp) - tp;
  }
}

// ---------- K7a (fallback path) ----------
__global__ __launch_bounds__(256) void k_score(const float* __restrict__ neigh,
                                               const float* __restrict__ samples,
                                               const float* __restrict__ degree,
                                               const float* __restrict__ mf,
                                               float* __restrict__ score) {
  const int g = blockIdx.x * 256 + threadIdx.x;
  const int b = g >> 11, i = g & 2047;
  const float sp = neigh[g] / degree[i];
  const float s = samples[g];
  const float tp = s / (s + mf[b]);
  score[g] = (2.0f - sp) - tp;
}

// ---------- K7b: stable rank + mask ----------
__global__ __launch_bounds__(256) void k_rank(const float* __restrict__ score,
                                              float* __restrict__ mask) {
  __shared__ float sc[NN];
  const int b = blockIdx.x >> 3, chunk = blockIdx.x & 7, t = threadIdx.x;
  const float* srow = score + (b << 11);
  #pragma unroll
  for (int q = 0; q < 8; ++q) sc[t + q * 256] = srow[t + q * 256];
  __syncthreads();
  const int i = chunk * 256 + t;
  const float si = sc[i];
  int less = 0, eqb = 0;
  for (int j = 0; j < NN; ++j) {
    const float sj = sc[j];
    less += (sj < si) ? 1 : 0;
    eqb += ((sj == si) && (j < i)) ? 1 : 0;
  }
  const int rank = less + eqb;
  mask[(b << 11) + i] = (rank < KEEP) ? 1.0f : 0.0f;
}

// ---------- K8: out = data * mask ----------
__global__ __launch_bounds__(256) void k_apply(const float* __restrict__ data,
                                               const float* __restrict__ mask,
                                               float* __restrict__ out) {
  const int g = blockIdx.x * 256 + threadIdx.x;
  const float4 d = ((const float4*)data)[g];
  const int idx = g << 2;
  const int b = idx >> 18;
  const int w = idx & 2047;
  const float4 mk = *(const float4*)(mask + (b << 11) + w);
  float4 o;
  o.x = d.x * mk.x; o.y = d.y * mk.y; o.z = d.z * mk.z; o.w = d.w * mk.w;
  ((float4*)out)[g] = o;
}

extern "C" void kernel_launch(void* const* d_in, const int* in_sizes, int n_in,
                              void* d_out, int out_size, void* d_ws, size_t ws_size,
                              hipStream_t stream) {
  (void)in_sizes; (void)n_in; (void)out_size;
  const float* data = (const float*)d_in[0];
  const float* adj  = (const float*)d_in[1];
  float* out = (float*)d_out;

  float* xnT   = out;             // fp32 Xn staged in output, overwritten last
  float* score = out + 2097152;   // total_score output slot (8*2048)

  uint8_t* w = (uint8_t*)d_ws;
  double* sq      = (double*)(w);            // 131072 B
  float*  kth     = (float*)(w + 131072);    // 65536 B
  float*  Rf      = (float*)(w + 196608);    // 32 B
  float*  samples = (float*)(w + 196672);    // 65536 B
  float*  neigh   = (float*)(w + 262208);    // 65536 B
  float*  mf      = (float*)(w + 327744);    // 32 B
  float*  degree  = (float*)(w + 327808);    // 8192 B
  float*  mask    = (float*)(w + 336000);    // 65536 B
  float*  distM   = (float*)(w + 1048576);   // 134217728 B

  const size_t distBytes = (size_t)BZ * NN * NN * sizeof(float);  // 134217728
  const bool fast = ws_size >= 1048576 + distBytes;

  k_norm<<<1024, 256, 0, stream>>>(data, xnT);
  k_sq  <<<64,   256, 0, stream>>>(xnT, sq);

  if (fast) {
    k_gemm_cyc16 <<<1024, 1024, 0, stream>>>(xnT, sq, distM);
    k_gemm_anti16<<<512,  256,  0, stream>>>(xnT, sq, distM);
    k_sel <<<4096, 256, 0, stream>>>(distM, kth);
    k_mean2048<<<8, 256, 0, stream>>>(kth, Rf);
    k_count_all<<<2048, 256, 0, stream>>>(distM, adj, Rf, samples, neigh, degree);
    k_scoremean<<<8, 256, 0, stream>>>(samples, neigh, degree, score);
  } else {
    k_dist<1><<<2048, 256, 0, stream>>>(xnT, sq, kth, nullptr, adj, Rf,
                                        samples, neigh, degree);
    k_mean2048<<<8, 256, 0, stream>>>(kth, Rf);
    k_dist<2><<<2048, 256, 0, stream>>>(xnT, sq, kth, nullptr, adj, Rf,
                                        samples, neigh, degree);
    k_mean2048<<<8, 256, 0, stream>>>(samples, mf);
    k_score<<<64, 256, 0, stream>>>(neigh, samples, degree, mf, score);
  }

  k_rank <<<64, 256, 0, stream>>>(score, mask);
  k_apply<<<2048, 256, 0, stream>>>(data, mask, out);
}

// Round 8
// 293.418 us; speedup vs baseline: 1.1444x; 1.1444x over previous
//
#include <hip/hip_runtime.h>
#include <math.h>

#define BZ   8
#define DDIM 128
#define NN   2048
#define KSEL 30
#define KEEP 1024
#define ROWS 8

// ---------- block reductions (blockDim == 256) ----------
__device__ __forceinline__ double blockReduceD(double x, double* lds) {
  #pragma unroll
  for (int off = 32; off; off >>= 1) x += __shfl_down(x, off, 64);
  int wv = threadIdx.x >> 6;
  __syncthreads();
  if ((threadIdx.x & 63) == 0) lds[wv] = x;
  __syncthreads();
  return lds[0] + lds[1] + lds[2] + lds[3];
}

__device__ __forceinline__ long long blockReduceLL(long long x, long long* lds) {
  #pragma unroll
  for (int off = 32; off; off >>= 1) x += __shfl_down(x, off, 64);
  int wv = threadIdx.x >> 6;
  __syncthreads();
  if ((threadIdx.x & 63) == 0) lds[wv] = x;
  __syncthreads();
  return lds[0] + lds[1] + lds[2] + lds[3];
}

// ---------- K1: per-(b,feature) mean/std(ddof=1) + normalize (fp32 out) ----
__global__ __launch_bounds__(256) void k_norm(const float* __restrict__ data,
                                              float* __restrict__ xnT) {
  __shared__ double lds[4];
  __shared__ float msd[2];
  const int blk = blockIdx.x;
  const int t = threadIdx.x;
  const float* src = data + (size_t)blk * NN;
  float* dst = xnT + (size_t)blk * NN;
  float v[8];
  double s = 0.0, s2 = 0.0;
  #pragma unroll
  for (int q = 0; q < 8; ++q) {
    v[q] = src[t + q * 256];
    double d = (double)v[q];
    s += d;
    s2 = fma(d, d, s2);
  }
  s  = blockReduceD(s, lds);
  s2 = blockReduceD(s2, lds);
  if (t == 0) {
    double mean = s * (1.0 / 2048.0);
    double var = (s2 - s * mean) / 2047.0;
    if (var < 0.0) var = 0.0;
    msd[0] = (float)mean;
    msd[1] = (float)sqrt(var);
  }
  __syncthreads();
  const float mean = msd[0];
  const float den = msd[1] + 1e-6f;
  #pragma unroll
  for (int q = 0; q < 8; ++q)
    dst[t + q * 256] = (v[q] - mean) / den;
}

// ---------- K2: sq[b][n] = sum_d Xn^2 (fp64 chain, fp32 input) ----------
__global__ __launch_bounds__(256) void k_sq(const float* __restrict__ xnT,
                                            double* __restrict__ sq) {
  const int g = blockIdx.x * 256 + threadIdx.x;
  const int b = g >> 11, n = g & 2047;
  const float* X = xnT + (size_t)b * DDIM * NN + n;
  double s = 0.0;
  for (int d = 0; d < DDIM; ++d) {
    double x = (double)X[(size_t)d * NN];
    s = fma(x, x, s);
  }
  sq[g] = s;
}

// ---------- K3: cyclic-halved symmetric fp64 distance GEMM (fp32 loads) ----
// Round-6 structure (8 rows x 4 cols/thread, 32 fma : 4 LDS-broadcast : 1
// global load per d) with fp32 float4 column loads widened in-register
// ((double)f exact -> bitwise-identical fma chain). Rowgroup g: rows
// [8g,8g+8), cols cyclic window [8g, 8g+1024). Separation 128 (antipodal)
// handled by k_gemm_anti. Stores [i][j] + bitwise-identical mirror [j][i].
__global__ __launch_bounds__(256, 3) void k_gemm_half(
    const float* __restrict__ xnT, const double* __restrict__ sq,
    float* __restrict__ distM) {
  __shared__ double rowd[DDIM][ROWS];   // 8 KB
  const int b = blockIdx.x & 7;
  const int g = blockIdx.x >> 3;        // 0..255
  const int i0 = g << 3;
  const int t = threadIdx.x;
  const float* Xb = xnT + (size_t)b * DDIM * NN;

  #pragma unroll
  for (int q = 0; q < 4; ++q) {
    const int idx = (t << 2) + q;       // 0..1023
    const int d = idx >> 3, r = idx & 7;
    rowd[d][r] = (double)Xb[((size_t)d << 11) + i0 + r];
  }
  __syncthreads();

  const int c = (i0 + (t << 2)) & (NN - 1);   // first of this thread's 4 cols

  double acc[ROWS][4];
  #pragma unroll
  for (int r = 0; r < ROWS; ++r)
    #pragma unroll
    for (int q = 0; q < 4; ++q) acc[r][q] = 0.0;

  const float* colp = Xb + c;
  #pragma unroll 2
  for (int d = 0; d < DDIM; ++d) {
    const float4 c0 = *(const float4*)(colp + ((size_t)d << 11));
    double cd[4];
    cd[0] = (double)c0.x; cd[1] = (double)c0.y;
    cd[2] = (double)c0.z; cd[3] = (double)c0.w;
    #pragma unroll
    for (int r = 0; r < ROWS; ++r) {
      const double rv = rowd[d][r];
      acc[r][0] = fma(rv, cd[0], acc[r][0]);
      acc[r][1] = fma(rv, cd[1], acc[r][1]);
      acc[r][2] = fma(rv, cd[2], acc[r][2]);
      acc[r][3] = fma(rv, cd[3], acc[r][3]);
    }
  }

  const double* sqb = sq + (b << 11);
  const double sqc0 = sqb[c], sqc1 = sqb[c + 1], sqc2 = sqb[c + 2], sqc3 = sqb[c + 3];
  float f[ROWS][4];
  #pragma unroll
  for (int r = 0; r < ROWS; ++r) {
    const double sqi = sqb[i0 + r];
    double d2;
    d2 = (sqi + sqc0) - 2.0 * acc[r][0]; if (d2 < 0.0) d2 = 0.0; f[r][0] = (float)sqrt(d2);
    d2 = (sqi + sqc1) - 2.0 * acc[r][1]; if (d2 < 0.0) d2 = 0.0; f[r][1] = (float)sqrt(d2);
    d2 = (sqi + sqc2) - 2.0 * acc[r][2]; if (d2 < 0.0) d2 = 0.0; f[r][2] = (float)sqrt(d2);
    d2 = (sqi + sqc3) - 2.0 * acc[r][3]; if (d2 < 0.0) d2 = 0.0; f[r][3] = (float)sqrt(d2);
    *(float4*)(distM + (((size_t)((b << 11) + i0 + r)) << 11) + c) =
        make_float4(f[r][0], f[r][1], f[r][2], f[r][3]);
  }
  // mirror store: rows c..c+3, cols i0..i0+7 (duplicates bitwise identical)
  #pragma unroll
  for (int q = 0; q < 4; ++q) {
    float* trow = distM + (((size_t)((b << 11) + c + q)) << 11) + i0;
    *(float4*)(trow)     = make_float4(f[0][q], f[1][q], f[2][q], f[3][q]);
    *(float4*)(trow + 4) = make_float4(f[4][q], f[5][q], f[6][q], f[7][q]);
  }
}

// ---------- K3a: antipodal 8x8 tiles (separation 128) ----------
// grid 1024: blk = g*8 + b, g in [0,128). Rows [8g,8g+8) x cols [8g+1024,+8).
// Same fp64 fma chain / rounding points; stores [i][j] and mirror [j][i].
__global__ __launch_bounds__(64) void k_gemm_anti(const float* __restrict__ xnT,
                                                  const double* __restrict__ sq,
                                                  float* __restrict__ distM) {
  __shared__ double rowd[DDIM][8];   // 8 KB
  __shared__ double cold[DDIM][8];   // 8 KB
  const int b = blockIdx.x & 7;
  const int g = blockIdx.x >> 3;      // 0..127
  const int i0 = g << 3;
  const int j0 = i0 + 1024;
  const int t = threadIdx.x;          // 0..63
  const float* Xb = xnT + (size_t)b * DDIM * NN;
  #pragma unroll
  for (int q = 0; q < 16; ++q) {
    const int idx = (t << 4) + q;     // 0..1023
    const int d = idx >> 3, r = idx & 7;
    rowd[d][r] = (double)Xb[((size_t)d << 11) + i0 + r];
    cold[d][r] = (double)Xb[((size_t)d << 11) + j0 + r];
  }
  __syncthreads();
  const int r = t >> 3, q = t & 7;
  double acc = 0.0;
  for (int d = 0; d < DDIM; ++d)
    acc = fma(rowd[d][r], cold[d][q], acc);
  const double* sqb = sq + (b << 11);
  double d2 = (sqb[i0 + r] + sqb[j0 + q]) - 2.0 * acc;
  if (d2 < 0.0) d2 = 0.0;
  const float f = (float)sqrt(d2);
  distM[(((size_t)((b << 11) + i0 + r)) << 11) + j0 + q] = f;
  distM[(((size_t)((b << 11) + j0 + q)) << 11) + i0 + r] = f;
}

// ---------- K3b: wave-per-row radix select (count(u<mid) form) ----------
__global__ __launch_bounds__(256) void k_sel(const float* __restrict__ dist,
                                             float* __restrict__ kth) {
  const int row = (blockIdx.x << 2) + (threadIdx.x >> 6);
  const int l = threadIdx.x & 63;
  const float4* r4 = (const float4*)(dist + ((size_t)row << 11));
  unsigned u[32];
  #pragma unroll
  for (int jj = 0; jj < 8; ++jj) {
    const float4 fv = r4[(jj << 6) + l];
    u[jj * 4 + 0] = __float_as_uint(fv.x);
    u[jj * 4 + 1] = __float_as_uint(fv.y);
    u[jj * 4 + 2] = __float_as_uint(fv.z);
    u[jj * 4 + 3] = __float_as_uint(fv.w);
  }
  unsigned pref = 0;
  for (int bit = 30; bit >= 0; --bit) {
    const unsigned mid = pref | (1u << bit);
    int c = 0;
    #pragma unroll
    for (int k = 0; k < 32; ++k)
      c += (int)__popcll(__ballot(u[k] < mid));
    if (c <= KSEL) pref = mid;
  }
  if (l == 0) kth[row] = __uint_as_float(pref);
}

// ---------- K4: mean of 2048 floats -> float ----------
__global__ __launch_bounds__(256) void k_mean2048(const float* __restrict__ in,
                                                  float* __restrict__ out) {
  __shared__ double lds[4];
  const int b = blockIdx.x, t = threadIdx.x;
  const float* p = in + (b << 11);
  double s = 0.0;
  #pragma unroll
  for (int q = 0; q < 8; ++q) s += (double)p[t + q * 256];
  s = blockReduceD(s, lds);
  if (t == 0) out[b] = (float)(s * (1.0 / 2048.0));
}

// ---------- K5: counts, one block per row i, all 8 batches ----------
__global__ __launch_bounds__(256) void k_count_all(
    const float* __restrict__ dist, const float* __restrict__ adj,
    const float* __restrict__ Rf,
    float* __restrict__ samples, float* __restrict__ neigh,
    float* __restrict__ degree) {
  __shared__ int pS[4], pN[4];
  const int i = blockIdx.x;
  const int t = threadIdx.x, w = t >> 6, l = t & 63;
  const float4* arow = (const float4*)(adj + ((size_t)i << 11)) + (t << 1);
  const float4 a0 = arow[0], a1 = arow[1];
  const float a[8] = {a0.x, a0.y, a0.z, a0.w, a1.x, a1.y, a1.z, a1.w};
  int dc = 0;
  #pragma unroll
  for (int q = 0; q < 8; ++q)
    dc += (int)__popcll(__ballot(a[q] != 0.0f));
  if (l == 0) pS[w] = dc;
  __syncthreads();
  if (t == 0) degree[i] = (float)(pS[0] + pS[1] + pS[2] + pS[3]);

  for (int b = 0; b < BZ; ++b) {
    const float R = Rf[b];
    const float4* drow =
        (const float4*)(dist + (((size_t)((b << 11) + i)) << 11)) + (t << 1);
    const float4 d0 = drow[0], d1 = drow[1];
    const float f[8] = {d0.x, d0.y, d0.z, d0.w, d1.x, d1.y, d1.z, d1.w};
    int sN = 0, nN = 0;
    #pragma unroll
    for (int q = 0; q < 8; ++q) {
      sN += (int)__popcll(__ballot(f[q] < R));
      nN += (int)__popcll(__ballot((a[q] != 0.0f) && (f[q] != 0.0f) && (f[q] < R)));
    }
    __syncthreads();
    if (l == 0) { pS[w] = sN; pN[w] = nN; }
    __syncthreads();
    if (t == 0) {
      samples[(b << 11) + i] = (float)(pS[0] + pS[1] + pS[2] + pS[3]);
      neigh[(b << 11) + i]   = (float)(pN[0] + pN[1] + pN[2] + pN[3]);
    }
  }
}

// ---------- tier-3 fallback (tiny ws): round-2 fused kernel ----------
template<int MODE>
__global__ __launch_bounds__(256, 2) void k_dist(
    const float* __restrict__ xnT, const double* __restrict__ sq,
    float* __restrict__ kth, float* __restrict__ distOut,
    const float* __restrict__ adj, const float* __restrict__ Rf,
    float* __restrict__ samples, float* __restrict__ neigh,
    float* __restrict__ degree) {
  __shared__ double rowd[DDIM][ROWS];
  __shared__ float dtile[ROWS][NN];
  __shared__ long long ldsLL[4];
  const int b = blockIdx.x >> 8;
  const int i0 = (blockIdx.x & 255) * ROWS;
  const int t = threadIdx.x;
  const float* Xb = xnT + (size_t)b * DDIM * NN;
  #pragma unroll
  for (int q = 0; q < 4; ++q) {
    const int idx = t + q * 256;
    const int d = idx >> 3, r = idx & 7;
    rowd[d][r] = (double)Xb[(size_t)d * NN + i0 + r];
  }
  __syncthreads();
  double acc[ROWS][8];
  #pragma unroll
  for (int r = 0; r < ROWS; ++r)
    #pragma unroll
    for (int q = 0; q < 8; ++q) acc[r][q] = 0.0;
  for (int d = 0; d < DDIM; ++d) {
    const float4* c4 = (const float4*)(Xb + ((size_t)d << 11)) + (t << 1);
    const float4 c0 = c4[0], c1 = c4[1];
    double cd[8];
    cd[0] = (double)c0.x; cd[1] = (double)c0.y;
    cd[2] = (double)c0.z; cd[3] = (double)c0.w;
    cd[4] = (double)c1.x; cd[5] = (double)c1.y;
    cd[6] = (double)c1.z; cd[7] = (double)c1.w;
    #pragma unroll
    for (int r = 0; r < ROWS; ++r) {
      const double rv = rowd[d][r];
      #pragma unroll
      for (int q = 0; q < 8; ++q) acc[r][q] = fma(rv, cd[q], acc[r][q]);
    }
  }
  const double* sqb = sq + (b << 11);
  const float R = (MODE == 2) ? Rf[b] : 0.0f;
  long long pk[ROWS];
  #pragma unroll
  for (int r = 0; r < ROWS; ++r) {
    const double sqi = sqb[i0 + r];
    float f8[8];
    #pragma unroll
    for (int q = 0; q < 8; ++q) {
      double d2 = (sqi + sqb[(t << 3) + q]) - 2.0 * acc[r][q];
      if (d2 < 0.0) d2 = 0.0;
      f8[q] = (float)sqrt(d2);
    }
    if (MODE < 2) {
      #pragma unroll
      for (int q = 0; q < 8; ++q) dtile[r][(t << 3) + q] = f8[q];
    } else {
      const float* arow = adj + (size_t)(i0 + r) * NN + (t << 3);
      int sN = 0, nN = 0, dc = 0;
      #pragma unroll
      for (int q = 0; q < 8; ++q) {
        const float a = arow[q];
        sN += (f8[q] < R) ? 1 : 0;
        nN += ((a != 0.0f) && (f8[q] != 0.0f) && (f8[q] < R)) ? 1 : 0;
        dc += (a != 0.0f) ? 1 : 0;
      }
      pk[r] = (long long)sN | ((long long)nN << 12) | ((long long)dc << 24);
    }
  }
  if (MODE < 2) {
    __syncthreads();
    const int w = t >> 6, l = t & 63;
    #pragma unroll
    for (int rr = 0; rr < 2; ++rr) {
      const int r = w * 2 + rr;
      unsigned u[32];
      #pragma unroll
      for (int k = 0; k < 32; ++k) u[k] = __float_as_uint(dtile[r][k * 64 + l]);
      unsigned pref = 0;
      int want = KSEL;
      for (int bit = 30; bit >= 0; --bit) {
        const unsigned ps = pref >> bit;
        int c = 0;
        #pragma unroll
        for (int k = 0; k < 32; ++k) c += ((u[k] >> bit) == ps) ? 1 : 0;
        #pragma unroll
        for (int off = 1; off < 64; off <<= 1) c += __shfl_xor(c, off, 64);
        if (want >= c) { want -= c; pref |= (1u << bit); }
      }
      if (l == 0) kth[(b << 11) + i0 + r] = __uint_as_float(pref);
    }
  } else {
    #pragma unroll
    for (int r = 0; r < ROWS; ++r) {
      const long long s = blockReduceLL(pk[r], ldsLL);
      if (t == 0) {
        const int g = (b << 11) + i0 + r;
        samples[g] = (float)(s & 0xFFF);
        neigh[g]   = (float)((s >> 12) & 0xFFF);
        if (b == 0) degree[i0 + r] = (float)((s >> 24) & 0xFFF);
      }
    }
  }
}

// ---------- K6+K7a fused: mf = mean(samples) then total_score ----------
__global__ __launch_bounds__(256) void k_scoremean(const float* __restrict__ samples,
                                                   const float* __restrict__ neigh,
                                                   const float* __restrict__ degree,
                                                   float* __restrict__ score) {
  __shared__ double lds[4];
  __shared__ float mfs;
  const int b = blockIdx.x, t = threadIdx.x;
  const float* p = samples + (b << 11);
  double s = 0.0;
  #pragma unroll
  for (int q = 0; q < 8; ++q) s += (double)p[t + q * 256];
  s = blockReduceD(s, lds);
  if (t == 0) mfs = (float)(s * (1.0 / 2048.0));
  __syncthreads();
  const float mf = mfs;
  #pragma unroll
  for (int q = 0; q < 8; ++q) {
    const int i = t + q * 256;
    const int g = (b << 11) + i;
    const float sp = neigh[g] / degree[i];
    const float sv = samples[g];
    const float tp = sv / (sv + mf);
    score[g] = (2.0f - sp) - tp;
  }
}

// ---------- K7a (fallback path) ----------
__global__ __launch_bounds__(256) void k_score(const float* __restrict__ neigh,
                                               const float* __restrict__ samples,
                                               const float* __restrict__ degree,
                                               const float* __restrict__ mf,
                                               float* __restrict__ score) {
  const int g = blockIdx.x * 256 + threadIdx.x;
  const int b = g >> 11, i = g & 2047;
  const float sp = neigh[g] / degree[i];
  const float s = samples[g];
  const float tp = s / (s + mf[b]);
  score[g] = (2.0f - sp) - tp;
}

// ---------- K7b: stable rank + mask ----------
__global__ __launch_bounds__(256) void k_rank(const float* __restrict__ score,
                                              float* __restrict__ mask) {
  __shared__ float sc[NN];
  const int b = blockIdx.x >> 3, chunk = blockIdx.x & 7, t = threadIdx.x;
  const float* srow = score + (b << 11);
  #pragma unroll
  for (int q = 0; q < 8; ++q) sc[t + q * 256] = srow[t + q * 256];
  __syncthreads();
  const int i = chunk * 256 + t;
  const float si = sc[i];
  int less = 0, eqb = 0;
  for (int j = 0; j < NN; ++j) {
    const float sj = sc[j];
    less += (sj < si) ? 1 : 0;
    eqb += ((sj == si) && (j < i)) ? 1 : 0;
  }
  const int rank = less + eqb;
  mask[(b << 11) + i] = (rank < KEEP) ? 1.0f : 0.0f;
}

// ---------- K8: out = data * mask ----------
__global__ __launch_bounds__(256) void k_apply(const float* __restrict__ data,
                                               const float* __restrict__ mask,
                                               float* __restrict__ out) {
  const int g = blockIdx.x * 256 + threadIdx.x;
  const float4 d = ((const float4*)data)[g];
  const int idx = g << 2;
  const int b = idx >> 18;
  const int w = idx & 2047;
  const float4 mk = *(const float4*)(mask + (b << 11) + w);
  float4 o;
  o.x = d.x * mk.x; o.y = d.y * mk.y; o.z = d.z * mk.z; o.w = d.w * mk.w;
  ((float4*)out)[g] = o;
}

extern "C" void kernel_launch(void* const* d_in, const int* in_sizes, int n_in,
                              void* d_out, int out_size, void* d_ws, size_t ws_size,
                              hipStream_t stream) {
  (void)in_sizes; (void)n_in; (void)out_size;
  const float* data = (const float*)d_in[0];
  const float* adj  = (const float*)d_in[1];
  float* out = (float*)d_out;

  float* xnT   = out;             // fp32 Xn staged in output, overwritten last
  float* score = out + 2097152;   // total_score output slot (8*2048)

  uint8_t* w = (uint8_t*)d_ws;
  double* sq      = (double*)(w);            // 131072 B
  float*  kth     = (float*)(w + 131072);    // 65536 B
  float*  Rf      = (float*)(w + 196608);    // 32 B
  float*  samples = (float*)(w + 196672);    // 65536 B
  float*  neigh   = (float*)(w + 262208);    // 65536 B
  float*  mf      = (float*)(w + 327744);    // 32 B
  float*  degree  = (float*)(w + 327808);    // 8192 B
  float*  mask    = (float*)(w + 336000);    // 65536 B
  float*  distM   = (float*)(w + 1048576);   // 134217728 B

  const size_t distBytes = (size_t)BZ * NN * NN * sizeof(float);  // 134217728
  const bool fast = ws_size >= 1048576 + distBytes;

  k_norm<<<1024, 256, 0, stream>>>(data, xnT);
  k_sq  <<<64,   256, 0, stream>>>(xnT, sq);

  if (fast) {
    k_gemm_half<<<2048, 256, 0, stream>>>(xnT, sq, distM);
    k_gemm_anti<<<1024, 64,  0, stream>>>(xnT, sq, distM);
    k_sel <<<4096, 256, 0, stream>>>(distM, kth);
    k_mean2048<<<8, 256, 0, stream>>>(kth, Rf);
    k_count_all<<<2048, 256, 0, stream>>>(distM, adj, Rf, samples, neigh, degree);
    k_scoremean<<<8, 256, 0, stream>>>(samples, neigh, degree, score);
  } else {
    k_dist<1><<<2048, 256, 0, stream>>>(xnT, sq, kth, nullptr, adj, Rf,
                                        samples, neigh, degree);
    k_mean2048<<<8, 256, 0, stream>>>(kth, Rf);
    k_dist<2><<<2048, 256, 0, stream>>>(xnT, sq, kth, nullptr, adj, Rf,
                                        samples, neigh, degree);
    k_mean2048<<<8, 256, 0, stream>>>(samples, mf);
    k_score<<<64, 256, 0, stream>>>(neigh, samples, degree, mf, score);
  }

  k_rank <<<64, 256, 0, stream>>>(score, mask);
  k_apply<<<2048, 256, 0, stream>>>(data, mask, out);
}

// Round 9
// 278.096 us; speedup vs baseline: 1.2075x; 1.0551x over previous
//
#include <hip/hip_runtime.h>
#include <math.h>

#define BZ   8
#define DDIM 128
#define NN   2048
#define KSEL 30
#define KEEP 1024
#define ROWS 8

// ---------- block reductions (blockDim == 256) ----------
__device__ __forceinline__ double blockReduceD(double x, double* lds) {
  #pragma unroll
  for (int off = 32; off; off >>= 1) x += __shfl_down(x, off, 64);
  int wv = threadIdx.x >> 6;
  __syncthreads();
  if ((threadIdx.x & 63) == 0) lds[wv] = x;
  __syncthreads();
  return lds[0] + lds[1] + lds[2] + lds[3];
}

__device__ __forceinline__ long long blockReduceLL(long long x, long long* lds) {
  #pragma unroll
  for (int off = 32; off; off >>= 1) x += __shfl_down(x, off, 64);
  int wv = threadIdx.x >> 6;
  __syncthreads();
  if ((threadIdx.x & 63) == 0) lds[wv] = x;
  __syncthreads();
  return lds[0] + lds[1] + lds[2] + lds[3];
}

// ---------- K1: normalize; PANEL=1 also emits fp64 row panel [b][g][d][8] --
template<int PANEL>
__global__ __launch_bounds__(256) void k_norm(const float* __restrict__ data,
                                              float* __restrict__ xnT,
                                              double* __restrict__ panelD) {
  __shared__ double lds[4];
  __shared__ float msd[2];
  const int blk = blockIdx.x;          // b*128 + d
  const int t = threadIdx.x;
  const float* src = data + (size_t)blk * NN;
  float* dst = xnT + (size_t)blk * NN;
  float v[8];
  double s = 0.0, s2 = 0.0;
  #pragma unroll
  for (int q = 0; q < 8; ++q) {
    v[q] = src[t + q * 256];
    double d = (double)v[q];
    s += d;
    s2 = fma(d, d, s2);
  }
  s  = blockReduceD(s, lds);
  s2 = blockReduceD(s2, lds);
  if (t == 0) {
    double mean = s * (1.0 / 2048.0);
    double var = (s2 - s * mean) / 2047.0;
    if (var < 0.0) var = 0.0;
    msd[0] = (float)mean;
    msd[1] = (float)sqrt(var);
  }
  __syncthreads();
  const float mean = msd[0];
  const float den = msd[1] + 1e-6f;
  const int b = blk >> 7, d = blk & 127;
  #pragma unroll
  for (int q = 0; q < 8; ++q) {
    const int n = t + q * 256;
    const float xn = (v[q] - mean) / den;   // fp32 rounding point (as before)
    dst[n] = xn;
    if (PANEL) {
      const int g = n >> 3, r = n & 7;
      panelD[(size_t)(b * 256 + g) * 1024 + d * 8 + r] = (double)xn; // exact
    }
  }
}

// ---------- K2: sq[b][n] = sum_d Xn^2 (fp64 chain, fp32 input) ----------
__global__ __launch_bounds__(256) void k_sq(const float* __restrict__ xnT,
                                            double* __restrict__ sq) {
  const int g = blockIdx.x * 256 + threadIdx.x;
  const int b = g >> 11, n = g & 2047;
  const float* X = xnT + (size_t)b * DDIM * NN + n;
  double s = 0.0;
  for (int d = 0; d < DDIM; ++d) {
    double x = (double)X[(size_t)d * NN];
    s = fma(x, x, s);
  }
  sq[g] = s;
}

// ---------- K3: cyclic-halved symmetric fp64 GEMM, SGPR rows, no LDS ------
// Blocks [0,2048): b=blk&7 (XCD pin), g=blk>>3; rows [8g,8g+8), cols cyclic
// window [8g, 8g+1024). Row values read block-uniformly from fp64 panel ->
// scalar loads, fma with SGPR operand; columns fp32 float4 + exact widen.
// Bitwise-identical fma chain to rounds 4-8. Separation-128 (antipodal)
// tiles handled by blocks [2048,2304) in the same launch.
__global__ __launch_bounds__(256, 4) void k_gemm_sgpr(
    const float* __restrict__ xnT, const double* __restrict__ panelD,
    const double* __restrict__ sq, float* __restrict__ distM) {
  const int t = threadIdx.x;

  if (blockIdx.x < 2048) {
    const int b = blockIdx.x & 7;
    const int g = blockIdx.x >> 3;        // 0..255
    const int i0 = g << 3;
    const int c = (i0 + (t << 2)) & (NN - 1);
    const float*  cp = xnT + (size_t)b * DDIM * NN + c;
    const double* rp = panelD + ((size_t)(b * 256 + g) << 10);   // [d][8]

    double acc[ROWS][4];
    #pragma unroll
    for (int r = 0; r < ROWS; ++r)
      #pragma unroll
      for (int q = 0; q < 4; ++q) acc[r][q] = 0.0;

    #pragma unroll 2
    for (int d = 0; d < DDIM; ++d) {
      const float4 c0 = *(const float4*)(cp + ((size_t)d << 11));
      const double cd0 = (double)c0.x, cd1 = (double)c0.y;
      const double cd2 = (double)c0.z, cd3 = (double)c0.w;
      #pragma unroll
      for (int r = 0; r < ROWS; ++r) {
        const double rv = rp[(d << 3) + r];   // uniform -> s_load
        acc[r][0] = fma(rv, cd0, acc[r][0]);
        acc[r][1] = fma(rv, cd1, acc[r][1]);
        acc[r][2] = fma(rv, cd2, acc[r][2]);
        acc[r][3] = fma(rv, cd3, acc[r][3]);
      }
    }

    const double* sqb = sq + (b << 11);
    const double sqc0 = sqb[c], sqc1 = sqb[c + 1], sqc2 = sqb[c + 2], sqc3 = sqb[c + 3];
    float f[ROWS][4];
    #pragma unroll
    for (int r = 0; r < ROWS; ++r) {
      const double sqi = sqb[i0 + r];
      double d2;
      d2 = (sqi + sqc0) - 2.0 * acc[r][0]; if (d2 < 0.0) d2 = 0.0; f[r][0] = (float)sqrt(d2);
      d2 = (sqi + sqc1) - 2.0 * acc[r][1]; if (d2 < 0.0) d2 = 0.0; f[r][1] = (float)sqrt(d2);
      d2 = (sqi + sqc2) - 2.0 * acc[r][2]; if (d2 < 0.0) d2 = 0.0; f[r][2] = (float)sqrt(d2);
      d2 = (sqi + sqc3) - 2.0 * acc[r][3]; if (d2 < 0.0) d2 = 0.0; f[r][3] = (float)sqrt(d2);
      *(float4*)(distM + (((size_t)((b << 11) + i0 + r)) << 11) + c) =
          make_float4(f[r][0], f[r][1], f[r][2], f[r][3]);
    }
    #pragma unroll
    for (int q = 0; q < 4; ++q) {
      float* trow = distM + (((size_t)((b << 11) + c + q)) << 11) + i0;
      *(float4*)(trow)     = make_float4(f[0][q], f[1][q], f[2][q], f[3][q]);
      *(float4*)(trow + 4) = make_float4(f[4][q], f[5][q], f[6][q], f[7][q]);
    }
  } else {
    // antipodal tiles: 4 8x8 tiles per block, one per 64-lane group
    const int a = (blockIdx.x - 2048) * 4 + (t >> 6);   // 0..1023
    const int b = a & 7;
    const int g = a >> 3;                                // 0..127
    const int i0 = g << 3;
    const int j0 = i0 + 1024;
    const int l = t & 63;
    const int r = l >> 3, q = l & 7;
    const double* rp = panelD + ((size_t)(b * 256 + g) << 10);
    const float*  cp = xnT + (size_t)b * DDIM * NN + j0 + q;
    double acc = 0.0;
    for (int d = 0; d < DDIM; ++d)
      acc = fma(rp[(d << 3) + r], (double)cp[(size_t)d << 11], acc);
    const double* sqb = sq + (b << 11);
    double d2 = (sqb[i0 + r] + sqb[j0 + q]) - 2.0 * acc;
    if (d2 < 0.0) d2 = 0.0;
    const float f = (float)sqrt(d2);
    distM[(((size_t)((b << 11) + i0 + r)) << 11) + j0 + q] = f;
    distM[(((size_t)((b << 11) + j0 + q)) << 11) + i0 + r] = f;
  }
}

// ---------- K3b: wave-per-row radix select (count(u<mid) form) ----------
__global__ __launch_bounds__(256) void k_sel(const float* __restrict__ dist,
                                             float* __restrict__ kth) {
  const int row = (blockIdx.x << 2) + (threadIdx.x >> 6);
  const int l = threadIdx.x & 63;
  const float4* r4 = (const float4*)(dist + ((size_t)row << 11));
  unsigned u[32];
  #pragma unroll
  for (int jj = 0; jj < 8; ++jj) {
    const float4 fv = r4[(jj << 6) + l];
    u[jj * 4 + 0] = __float_as_uint(fv.x);
    u[jj * 4 + 1] = __float_as_uint(fv.y);
    u[jj * 4 + 2] = __float_as_uint(fv.z);
    u[jj * 4 + 3] = __float_as_uint(fv.w);
  }
  unsigned pref = 0;
  for (int bit = 30; bit >= 0; --bit) {
    const unsigned mid = pref | (1u << bit);
    int c = 0;
    #pragma unroll
    for (int k = 0; k < 32; ++k)
      c += (int)__popcll(__ballot(u[k] < mid));
    if (c <= KSEL) pref = mid;
  }
  if (l == 0) kth[row] = __uint_as_float(pref);
}

// ---------- K4: mean of 2048 floats -> float ----------
__global__ __launch_bounds__(256) void k_mean2048(const float* __restrict__ in,
                                                  float* __restrict__ out) {
  __shared__ double lds[4];
  const int b = blockIdx.x, t = threadIdx.x;
  const float* p = in + (b << 11);
  double s = 0.0;
  #pragma unroll
  for (int q = 0; q < 8; ++q) s += (double)p[t + q * 256];
  s = blockReduceD(s, lds);
  if (t == 0) out[b] = (float)(s * (1.0 / 2048.0));
}

// ---------- K5: counts; samples by row scan, neighbors by king-move gather -
// adj == _grid_adj(32,64): adj[i][j]!=0 iff j is an in-bounds king neighbor
// of i (d2 in {1,2}) -> neighbor_N/degree need only 8 gathered values.
__global__ __launch_bounds__(256) void k_count_geo(
    const float* __restrict__ dist, const float* __restrict__ Rf,
    float* __restrict__ samples, float* __restrict__ neigh,
    float* __restrict__ degree) {
  __shared__ int pS[4];
  const int bi = blockIdx.x;            // b*2048 + i
  const int b = bi >> 11, i = bi & 2047;
  const int t = threadIdx.x, w = t >> 6, l = t & 63;
  const float R = Rf[b];
  const float* drow = dist + ((size_t)bi << 11);
  const float4* d4 = (const float4*)drow + (t << 1);
  const float4 d0 = d4[0], d1 = d4[1];
  const float f[8] = {d0.x, d0.y, d0.z, d0.w, d1.x, d1.y, d1.z, d1.w};
  int sN = 0;
  #pragma unroll
  for (int q = 0; q < 8; ++q) sN += (int)__popcll(__ballot(f[q] < R));
  if (l == 0) pS[w] = sN;
  __syncthreads();
  if (t < 64) {
    bool inb = false, ok = false;
    if (l < 8) {
      const int m = (l < 4) ? l : l + 1;          // skip (0,0): m in [0,9)\{4}
      const int di = m / 3 - 1, dj = m % 3 - 1;   // king-move offsets
      const int rj = (i >> 6) + di, cj = (i & 63) + dj;
      inb = ((unsigned)rj < 32u) && ((unsigned)cj < 64u);
      if (inb) {
        const float fv = drow[(rj << 6) + cj];
        ok = (fv != 0.0f) && (fv < R);            // adj_distance semantics
      }
    }
    const int nN = (int)__popcll(__ballot(ok));
    const int dc = (int)__popcll(__ballot(inb));
    if (t == 0) {
      samples[bi] = (float)(pS[0] + pS[1] + pS[2] + pS[3]);
      neigh[bi]   = (float)nN;
      if (b == 0) degree[i] = (float)dc;
    }
  }
}

// ---------- K6: fused mean(samples) + total_score + stable rank + mask -----
// 64 blocks (b = blk>>3, chunk = blk&7); every block recomputes all 2048
// scores into LDS (identical fp32 ops as before); chunk-0 writes score out.
__global__ __launch_bounds__(256) void k_rank_score(
    const float* __restrict__ samples, const float* __restrict__ neigh,
    const float* __restrict__ degree, float* __restrict__ score,
    float* __restrict__ mask) {
  __shared__ double lds[4];
  __shared__ float mfs;
  __shared__ float sc[NN];
  const int b = blockIdx.x >> 3, chunk = blockIdx.x & 7, t = threadIdx.x;
  const float* p = samples + (b << 11);
  double s = 0.0;
  #pragma unroll
  for (int q = 0; q < 8; ++q) s += (double)p[t + q * 256];
  s = blockReduceD(s, lds);
  if (t == 0) mfs = (float)(s * (1.0 / 2048.0));
  __syncthreads();
  const float mf = mfs;
  #pragma unroll
  for (int q = 0; q < 8; ++q) {
    const int i = t + q * 256;
    const int g = (b << 11) + i;
    const float sp = neigh[g] / degree[i];
    const float sv = p[i];
    const float tp = sv / (sv + mf);
    const float v = (2.0f - sp) - tp;
    sc[i] = v;
    if (chunk == 0) score[g] = v;
  }
  __syncthreads();
  const int i = chunk * 256 + t;
  const float si = sc[i];
  int less = 0, eqb = 0;
  for (int j = 0; j < NN; ++j) {
    const float sj = sc[j];
    less += (sj < si) ? 1 : 0;
    eqb  += ((sj == si) && (j < i)) ? 1 : 0;
  }
  mask[(b << 11) + i] = ((less + eqb) < KEEP) ? 1.0f : 0.0f;
}

// ---------- K7: out = data * mask ----------
__global__ __launch_bounds__(256) void k_apply(const float* __restrict__ data,
                                               const float* __restrict__ mask,
                                               float* __restrict__ out) {
  const int g = blockIdx.x * 256 + threadIdx.x;
  const float4 d = ((const float4*)data)[g];
  const int idx = g << 2;
  const int b = idx >> 18;
  const int w = idx & 2047;
  const float4 mk = *(const float4*)(mask + (b << 11) + w);
  float4 o;
  o.x = d.x * mk.x; o.y = d.y * mk.y; o.z = d.z * mk.z; o.w = d.w * mk.w;
  ((float4*)out)[g] = o;
}

// ---------- tier-2 fallback (tiny ws): round-2 fused kernel ----------
template<int MODE>
__global__ __launch_bounds__(256, 2) void k_dist(
    const float* __restrict__ xnT, const double* __restrict__ sq,
    float* __restrict__ kth, float* __restrict__ distOut,
    const float* __restrict__ adj, const float* __restrict__ Rf,
    float* __restrict__ samples, float* __restrict__ neigh,
    float* __restrict__ degree) {
  __shared__ double rowd[DDIM][ROWS];
  __shared__ float dtile[ROWS][NN];
  __shared__ long long ldsLL[4];
  const int b = blockIdx.x >> 8;
  const int i0 = (blockIdx.x & 255) * ROWS;
  const int t = threadIdx.x;
  const float* Xb = xnT + (size_t)b * DDIM * NN;
  #pragma unroll
  for (int q = 0; q < 4; ++q) {
    const int idx = t + q * 256;
    const int d = idx >> 3, r = idx & 7;
    rowd[d][r] = (double)Xb[(size_t)d * NN + i0 + r];
  }
  __syncthreads();
  double acc[ROWS][8];
  #pragma unroll
  for (int r = 0; r < ROWS; ++r)
    #pragma unroll
    for (int q = 0; q < 8; ++q) acc[r][q] = 0.0;
  for (int d = 0; d < DDIM; ++d) {
    const float4* c4 = (const float4*)(Xb + ((size_t)d << 11)) + (t << 1);
    const float4 c0 = c4[0], c1 = c4[1];
    double cd[8];
    cd[0] = (double)c0.x; cd[1] = (double)c0.y;
    cd[2] = (double)c0.z; cd[3] = (double)c0.w;
    cd[4] = (double)c1.x; cd[5] = (double)c1.y;
    cd[6] = (double)c1.z; cd[7] = (double)c1.w;
    #pragma unroll
    for (int r = 0; r < ROWS; ++r) {
      const double rv = rowd[d][r];
      #pragma unroll
      for (int q = 0; q < 8; ++q) acc[r][q] = fma(rv, cd[q], acc[r][q]);
    }
  }
  const double* sqb = sq + (b << 11);
  const float R = (MODE == 2) ? Rf[b] : 0.0f;
  long long pk[ROWS];
  #pragma unroll
  for (int r = 0; r < ROWS; ++r) {
    const double sqi = sqb[i0 + r];
    float f8[8];
    #pragma unroll
    for (int q = 0; q < 8; ++q) {
      double d2 = (sqi + sqb[(t << 3) + q]) - 2.0 * acc[r][q];
      if (d2 < 0.0) d2 = 0.0;
      f8[q] = (float)sqrt(d2);
    }
    if (MODE < 2) {
      #pragma unroll
      for (int q = 0; q < 8; ++q) dtile[r][(t << 3) + q] = f8[q];
    } else {
      const float* arow = adj + (size_t)(i0 + r) * NN + (t << 3);
      int sN = 0, nN = 0, dc = 0;
      #pragma unroll
      for (int q = 0; q < 8; ++q) {
        const float a = arow[q];
        sN += (f8[q] < R) ? 1 : 0;
        nN += ((a != 0.0f) && (f8[q] != 0.0f) && (f8[q] < R)) ? 1 : 0;
        dc += (a != 0.0f) ? 1 : 0;
      }
      pk[r] = (long long)sN | ((long long)nN << 12) | ((long long)dc << 24);
    }
  }
  if (MODE < 2) {
    __syncthreads();
    const int w = t >> 6, l = t & 63;
    #pragma unroll
    for (int rr = 0; rr < 2; ++rr) {
      const int r = w * 2 + rr;
      unsigned u[32];
      #pragma unroll
      for (int k = 0; k < 32; ++k) u[k] = __float_as_uint(dtile[r][k * 64 + l]);
      unsigned pref = 0;
      int want = KSEL;
      for (int bit = 30; bit >= 0; --bit) {
        const unsigned ps = pref >> bit;
        int c = 0;
        #pragma unroll
        for (int k = 0; k < 32; ++k) c += ((u[k] >> bit) == ps) ? 1 : 0;
        #pragma unroll
        for (int off = 1; off < 64; off <<= 1) c += __shfl_xor(c, off, 64);
        if (want >= c) { want -= c; pref |= (1u << bit); }
      }
      if (l == 0) kth[(b << 11) + i0 + r] = __uint_as_float(pref);
    }
  } else {
    #pragma unroll
    for (int r = 0; r < ROWS; ++r) {
      const long long s = blockReduceLL(pk[r], ldsLL);
      if (t == 0) {
        const int g = (b << 11) + i0 + r;
        samples[g] = (float)(s & 0xFFF);
        neigh[g]   = (float)((s >> 12) & 0xFFF);
        if (b == 0) degree[i0 + r] = (float)((s >> 24) & 0xFFF);
      }
    }
  }
}

// ---------- fallback score ----------
__global__ __launch_bounds__(256) void k_score(const float* __restrict__ neigh,
                                               const float* __restrict__ samples,
                                               const float* __restrict__ degree,
                                               const float* __restrict__ mf,
                                               float* __restrict__ score) {
  const int g = blockIdx.x * 256 + threadIdx.x;
  const int b = g >> 11, i = g & 2047;
  const float sp = neigh[g] / degree[i];
  const float s = samples[g];
  const float tp = s / (s + mf[b]);
  score[g] = (2.0f - sp) - tp;
}

// ---------- fallback rank ----------
__global__ __launch_bounds__(256) void k_rank(const float* __restrict__ score,
                                              float* __restrict__ mask) {
  __shared__ float sc[NN];
  const int b = blockIdx.x >> 3, chunk = blockIdx.x & 7, t = threadIdx.x;
  const float* srow = score + (b << 11);
  #pragma unroll
  for (int q = 0; q < 8; ++q) sc[t + q * 256] = srow[t + q * 256];
  __syncthreads();
  const int i = chunk * 256 + t;
  const float si = sc[i];
  int less = 0, eqb = 0;
  for (int j = 0; j < NN; ++j) {
    const float sj = sc[j];
    less += (sj < si) ? 1 : 0;
    eqb += ((sj == si) && (j < i)) ? 1 : 0;
  }
  const int rank = less + eqb;
  mask[(b << 11) + i] = (rank < KEEP) ? 1.0f : 0.0f;
}

extern "C" void kernel_launch(void* const* d_in, const int* in_sizes, int n_in,
                              void* d_out, int out_size, void* d_ws, size_t ws_size,
                              hipStream_t stream) {
  (void)in_sizes; (void)n_in; (void)out_size;
  const float* data = (const float*)d_in[0];
  const float* adj  = (const float*)d_in[1];
  float* out = (float*)d_out;

  float* xnT   = out;             // fp32 Xn staged in output, overwritten last
  float* score = out + 2097152;   // total_score output slot (8*2048)

  uint8_t* w = (uint8_t*)d_ws;
  double* sq      = (double*)(w);            // 131072 B
  float*  kth     = (float*)(w + 131072);    // 65536 B
  float*  Rf      = (float*)(w + 196608);    // 32 B
  float*  samples = (float*)(w + 196672);    // 65536 B
  float*  neigh   = (float*)(w + 262208);    // 65536 B
  float*  mf      = (float*)(w + 327744);    // 32 B
  float*  degree  = (float*)(w + 327808);    // 8192 B
  float*  mask    = (float*)(w + 336000);    // 65536 B

  const size_t panelBytes = (size_t)BZ * DDIM * NN * sizeof(double); // 16777216
  const size_t distBytes  = (size_t)BZ * NN * NN * sizeof(float);    // 134217728

  double* panelD = (double*)(w + 1048576);
  float*  distM  = (float*)(w + 1048576 + panelBytes);

  const bool fast = ws_size >= 1048576 + panelBytes + distBytes;

  if (fast) {
    k_norm<1><<<1024, 256, 0, stream>>>(data, xnT, panelD);
    k_sq  <<<64,   256, 0, stream>>>(xnT, sq);
    k_gemm_sgpr<<<2304, 256, 0, stream>>>(xnT, panelD, sq, distM);
    k_sel <<<4096, 256, 0, stream>>>(distM, kth);
    k_mean2048<<<8, 256, 0, stream>>>(kth, Rf);
    k_count_geo<<<16384, 256, 0, stream>>>(distM, Rf, samples, neigh, degree);
    k_rank_score<<<64, 256, 0, stream>>>(samples, neigh, degree, score, mask);
  } else {
    k_norm<0><<<1024, 256, 0, stream>>>(data, xnT, nullptr);
    k_sq  <<<64, 256, 0, stream>>>(xnT, sq);
    k_dist<1><<<2048, 256, 0, stream>>>(xnT, sq, kth, nullptr, adj, Rf,
                                        samples, neigh, degree);
    k_mean2048<<<8, 256, 0, stream>>>(kth, Rf);
    k_dist<2><<<2048, 256, 0, stream>>>(xnT, sq, kth, nullptr, adj, Rf,
                                        samples, neigh, degree);
    k_mean2048<<<8, 256, 0, stream>>>(samples, mf);
    k_score<<<64, 256, 0, stream>>>(neigh, samples, degree, mf, score);
    k_rank <<<64, 256, 0, stream>>>(score, mask);
  }

  k_apply<<<2048, 256, 0, stream>>>(data, mask, out);
}